// Round 15
// baseline (189.176 us; speedup 1.0000x reference)
//
#include <hip/hip_runtime.h>

// LinearAttention on MI355X — round 15 = round 13 (best, 181.5us) + T1 XCD
// swizzle on gemm_qkv / gemm_out (bijective remap, nwg%8==0; consecutive work
// units -> same XCD -> operand-panel L2 reuse). gemm_ctx has no inter-block
// reuse -> unswizzled.
// ws: S1=0: xnT -> P(8MB) + M@+8M | S2=33.5M: qT | S3=67.1M: kv -> out2T
//     E=134217728: wbf(1.5M) | woutbf@135790592 | sden@136314880 (16KB)

typedef unsigned short u16;
typedef __attribute__((ext_vector_type(8))) short short8;
typedef __attribute__((ext_vector_type(4))) short short4_t;
typedef __attribute__((ext_vector_type(4))) float f32x4;

static constexpr size_t XN_B = (size_t)512 * 4096;
static constexpr size_t KV_B = (size_t)1024 * 4096;
static constexpr float SQRT512 = 22.62741699796952f;

typedef const __attribute__((address_space(1))) unsigned int gu32;
typedef __attribute__((address_space(3))) unsigned int lu32;

__device__ __forceinline__ float b2f(u16 u){
  union { unsigned u; float f; } x; x.u = ((unsigned)u) << 16; return x.f;
}
__device__ __forceinline__ u16 f2b(float f){
  union { float f; unsigned u; } x; x.f = f;
  unsigned r = x.u + 0x7FFFu + ((x.u >> 16) & 1u);   // RNE
  return (u16)(r >> 16);
}
__device__ __forceinline__ void gl16(const u16* g, u16* l){
  __builtin_amdgcn_global_load_lds((gu32*)g, (lu32*)l, 16, 0, 0);
}
// bijective XCD-aware remap (requires nwg % 8 == 0): hardware block bid sits
// on XCD bid%8; it computes work unit (bid%8)*(nwg/8) + bid/8 so consecutive
// work units co-reside on one XCD's L2.
__device__ __forceinline__ int xswz(int bid, int nwg){
  return (bid & 7) * (nwg >> 3) + (bid >> 3);
}

// ---- kprep: blocks 0-1023 convert weights (g1 folded into wqkv; blocks 0-15
//      also zero sden); blocks 1024-2047 fused rms1 (x -> xnT [p][c] bf16)
__global__ __launch_bounds__(256)
void kprep(const float* __restrict__ wqkv, const float* __restrict__ wout,
           const float* __restrict__ g1, u16* __restrict__ dq, u16* __restrict__ dw,
           const float* __restrict__ x, u16* __restrict__ xnT,
           float* __restrict__ sden){
  __shared__ u16 lt[32][514];
  __shared__ float red[256];
  __shared__ float invs[32];
  int bid = blockIdx.x;
  int t = threadIdx.x;
  if (bid < 1024){
    if (bid < 16) sden[bid * 256 + t] = 0.f;
    size_t i = ((size_t)bid * 256 + t) * 4;
    short4_t o;
    if (i < (size_t)786432){
      f32x4 v = *(const f32x4*)(wqkv + i);
      int c = (int)(i & 511);
      #pragma unroll
      for (int j = 0; j < 4; j++) o[j] = (short)f2b(v[j] * g1[c + j] * SQRT512);
      *(short4_t*)(dq + i) = o;
    } else {
      size_t off = i - 786432;
      f32x4 v = *(const f32x4*)(wout + off);
      #pragma unroll
      for (int j = 0; j < 4; j++) o[j] = (short)f2b(v[j]);
      *(short4_t*)(dw + off) = o;
    }
    return;
  }
  int pg0 = (bid - 1024) * 32;
  int b = pg0 >> 12, p0 = pg0 & 4095;
  int px = t & 31, chunk = t >> 5;
  const float* xp = x + (size_t)b * XN_B + p0 + px;
  float s = 0.f;
  #pragma unroll 4
  for (int c = chunk * 64; c < chunk * 64 + 64; ++c){
    float v = xp[(size_t)c * 4096];
    lt[px][c] = f2b(v);
    s += v * v;
  }
  red[t] = s;
  __syncthreads();
  if (chunk == 0){
    float tt = red[px] + red[px + 32] + red[px + 64] + red[px + 96]
             + red[px + 128] + red[px + 160] + red[px + 192] + red[px + 224];
    invs[px] = rsqrtf(tt + 1e-12f);
  }
  __syncthreads();
  int px2 = t >> 3, c0 = (t & 7) * 8;
  float iv = invs[px2];
  u16* dst = xnT + (size_t)(pg0 + px2) * 512;
  #pragma unroll
  for (int j = 0; j < 8; j++){
    int c = c0 + j * 64;
    short8 o;
    #pragma unroll
    for (int e = 0; e < 8; e++) o[e] = (short)f2b(b2f(lt[px2][c + e]) * iv);
    *(short8*)(dst + c) = o;
  }
}

// ---- merged qT + kv GEMM, XCD-swizzled. 128^2 tile, BK=64 dbuf, counted
// vmcnt(8), XOR swizzle (round-5 loop). Work 0-2047: kv_b = Wkv @ xn_b.
// Work 2048-3071: qT = softmax_d(xnT @ Wq^T)/8 (SMAX epilogue).
__global__ __launch_bounds__(256)
void gemm_qkv(const u16* __restrict__ Wkv, const u16* __restrict__ wq,
              const u16* __restrict__ xnT, u16* __restrict__ kvb,
              u16* __restrict__ qT)
{
  constexpr int NT = 8;                 // K=512 / BK=64
  const int bid = xswz(blockIdx.x, 3072);
  const u16* A; const u16* BT; u16* C;
  int m0, n0; size_t ldc; bool smax;
  if (bid < 2048){
    int ntile = bid & 31, mtile = (bid >> 5) & 7, z = bid >> 8;
    A = Wkv; BT = xnT + (size_t)z * XN_B; C = kvb + (size_t)z * KV_B;
    m0 = mtile * 128; n0 = ntile * 128; ldc = 4096; smax = false;
  } else {
    int idx = bid - 2048;
    int ntile = idx & 3, mtile = idx >> 2;
    A = xnT; BT = wq; C = qT;
    m0 = mtile * 128; n0 = ntile * 128; ldc = 512; smax = true;
  }
  __shared__ u16 As[2][128 * 64];
  __shared__ u16 Bs[2][128 * 64];
  const int tid = threadIdx.x;
  const int srow0 = tid >> 3;           // 32 rows per staging group
  const int schunk = tid & 7;           // 16B chunk slot within 128B row
  const int lane = tid & 63, wid = tid >> 6;
  const int wr = (wid >> 1) * 64, wc = (wid & 1) * 64;
  const int fr = lane & 15, fq = lane >> 4;
  f32x4 acc[4][4] = {};

  auto STAGE = [&](int s, int t){
    const int k0 = t * 64;
    #pragma unroll
    for (int r = 0; r < 4; r++){
      int row = r * 32 + srow0;
      int gj = (schunk ^ (row & 7)) * 8;
      gl16(A  + (size_t)(m0 + row) * 512 + k0 + gj, &As[s][0] + r * 2048 + tid * 8);
      gl16(BT + (size_t)(n0 + row) * 512 + k0 + gj, &Bs[s][0] + r * 2048 + tid * 8);
    }
  };

  STAGE(0, 0);
  int cur = 0;
  for (int t = 0; t < NT; t++){
    if (t + 1 < NT){
      STAGE(cur ^ 1, t + 1);
      asm volatile("s_waitcnt vmcnt(8)" ::: "memory");
    } else {
      asm volatile("s_waitcnt vmcnt(0)" ::: "memory");
    }
    __builtin_amdgcn_s_barrier();
    __builtin_amdgcn_sched_barrier(0);
    #pragma unroll
    for (int ks = 0; ks < 2; ks++){
      short8 a[4], b[4];
      #pragma unroll
      for (int i = 0; i < 4; i++){
        int ra = wr + i * 16 + fr;
        a[i] = *(const short8*)(&As[cur][0] + ra * 64 + ((ks * 4 + fq) ^ (ra & 7)) * 8);
        int rb = wc + i * 16 + fr;
        b[i] = *(const short8*)(&Bs[cur][0] + rb * 64 + ((ks * 4 + fq) ^ (rb & 7)) * 8);
      }
      #pragma unroll
      for (int i = 0; i < 4; i++)
        #pragma unroll
        for (int j = 0; j < 4; j++)
          acc[i][j] = __builtin_amdgcn_mfma_f32_16x16x32_bf16(a[i], b[j], acc[i][j], 0, 0, 0);
    }
    __builtin_amdgcn_sched_barrier(0);
    __builtin_amdgcn_s_barrier();
    cur ^= 1;
  }

  if (smax){
    // softmax over each row's 64-col quadrant (= one head), then /8
    #pragma unroll
    for (int i = 0; i < 4; i++)
      #pragma unroll
      for (int e = 0; e < 4; e++){
        float mx = fmaxf(fmaxf(acc[i][0][e], acc[i][1][e]),
                         fmaxf(acc[i][2][e], acc[i][3][e]));
        mx = fmaxf(mx, __shfl_xor(mx, 1));
        mx = fmaxf(mx, __shfl_xor(mx, 2));
        mx = fmaxf(mx, __shfl_xor(mx, 4));
        mx = fmaxf(mx, __shfl_xor(mx, 8));
        float p0 = __expf(acc[i][0][e] - mx);
        float p1 = __expf(acc[i][1][e] - mx);
        float p2 = __expf(acc[i][2][e] - mx);
        float p3 = __expf(acc[i][3][e] - mx);
        float s = p0 + p1 + p2 + p3;
        s += __shfl_xor(s, 1);
        s += __shfl_xor(s, 2);
        s += __shfl_xor(s, 4);
        s += __shfl_xor(s, 8);
        float r = 1.f / (s * 8.0f);    // SCALE = sqrt(64) = 8
        acc[i][0][e] = p0 * r; acc[i][1][e] = p1 * r;
        acc[i][2][e] = p2 * r; acc[i][3][e] = p3 * r;
      }
  }
  #pragma unroll
  for (int i = 0; i < 4; i++)
    #pragma unroll
    for (int j = 0; j < 4; j++)
      #pragma unroll
      for (int e = 0; e < 4; e++){
        int row = m0 + wr + i * 16 + fq * 4 + e;
        int col = n0 + wc + j * 16 + fr;
        C[(size_t)row * ldc + col] = f2b(acc[i][j][e]);
      }
}

// ---- out2 GEMM, XCD-swizzled: out2T_b = qT_b @ M_b^T + bias
// (M=4096,N=512,K=512/batch). 128^2/BK=64 structure, 1024 work units.
__global__ __launch_bounds__(256)
void gemm_out(const u16* __restrict__ qT, const u16* __restrict__ Mb,
              u16* __restrict__ out2T, const float* __restrict__ bias)
{
  constexpr int NT = 8;
  const int bid = xswz(blockIdx.x, 1024);
  const int xt = bid & 3, yt = (bid >> 2) & 31, z = bid >> 7;
  const u16* A  = qT + (size_t)z * 4096 * 512;
  const u16* BT = Mb + (size_t)z * 262144;
  u16* C = out2T + (size_t)z * 4096 * 512;
  const int m0 = yt * 128, n0 = xt * 128;
  __shared__ u16 As[2][128 * 64];
  __shared__ u16 Bs[2][128 * 64];
  const int tid = threadIdx.x;
  const int srow0 = tid >> 3;
  const int schunk = tid & 7;
  const int lane = tid & 63, wid = tid >> 6;
  const int wr = (wid >> 1) * 64, wc = (wid & 1) * 64;
  const int fr = lane & 15, fq = lane >> 4;
  f32x4 acc[4][4] = {};

  auto STAGE = [&](int s, int t){
    const int k0 = t * 64;
    #pragma unroll
    for (int r = 0; r < 4; r++){
      int row = r * 32 + srow0;
      int gj = (schunk ^ (row & 7)) * 8;
      gl16(A  + (size_t)(m0 + row) * 512 + k0 + gj, &As[s][0] + r * 2048 + tid * 8);
      gl16(BT + (size_t)(n0 + row) * 512 + k0 + gj, &Bs[s][0] + r * 2048 + tid * 8);
    }
  };

  STAGE(0, 0);
  int cur = 0;
  for (int t = 0; t < NT; t++){
    if (t + 1 < NT){
      STAGE(cur ^ 1, t + 1);
      asm volatile("s_waitcnt vmcnt(8)" ::: "memory");
    } else {
      asm volatile("s_waitcnt vmcnt(0)" ::: "memory");
    }
    __builtin_amdgcn_s_barrier();
    __builtin_amdgcn_sched_barrier(0);
    #pragma unroll
    for (int ks = 0; ks < 2; ks++){
      short8 a[4], b[4];
      #pragma unroll
      for (int i = 0; i < 4; i++){
        int ra = wr + i * 16 + fr;
        a[i] = *(const short8*)(&As[cur][0] + ra * 64 + ((ks * 4 + fq) ^ (ra & 7)) * 8);
        int rb = wc + i * 16 + fr;
        b[i] = *(const short8*)(&Bs[cur][0] + rb * 64 + ((ks * 4 + fq) ^ (rb & 7)) * 8);
      }
      #pragma unroll
      for (int i = 0; i < 4; i++)
        #pragma unroll
        for (int j = 0; j < 4; j++)
          acc[i][j] = __builtin_amdgcn_mfma_f32_16x16x32_bf16(a[i], b[j], acc[i][j], 0, 0, 0);
    }
    __builtin_amdgcn_sched_barrier(0);
    __builtin_amdgcn_s_barrier();
    cur ^= 1;
  }

  #pragma unroll
  for (int i = 0; i < 4; i++)
    #pragma unroll
    for (int j = 0; j < 4; j++)
      #pragma unroll
      for (int e = 0; e < 4; e++){
        int row = m0 + wr + i * 16 + fq * 4 + e;
        int col = n0 + wc + j * 16 + fr;
        C[(size_t)row * 512 + col] = f2b(acc[i][j][e] + bias[col]);
      }
}

// ---- ctx split-K(8) partials: P[z=bh*8+s][d][e] f32. Stages UNNORMALIZED
// exp(k); accumulates the row expsum during staging -> atomicAdd into sden.
__global__ __launch_bounds__(256)
void gemm_ctx(const u16* __restrict__ kv, float* __restrict__ P,
              float* __restrict__ sden)
{
  constexpr int K = 512;                     // 4096 / 8 splits
  const int z = blockIdx.z;
  const int tid = threadIdx.x;
  const int ar = tid >> 2, ac = (tid & 3) * 8;
  int bh = z >> 3, sp = z & 7, b = bh >> 3, h = bh & 7;
  const u16* A  = kv + (size_t)b * KV_B + (size_t)(h * 64) * 4096 + sp * 512;
  const u16* BT = kv + (size_t)b * KV_B + (size_t)(512 + h * 64) * 4096 + sp * 512;
  __shared__ u16 As[64 * 40];
  __shared__ u16 Bs[64 * 40];
  const int wid = tid >> 6, lane = tid & 63;
  const int wr = (wid >> 1) * 32, wc = (wid & 1) * 32;
  const int lr = lane & 15, kb = lane >> 4;
  f32x4 acc[2][2] = {};
  float ssum = 0.f;
  for (int k0 = 0; k0 < K; k0 += 32){
    short8 av = *(const short8*)(A + (size_t)ar * 4096 + k0 + ac);
    short8 ao;
    #pragma unroll
    for (int e = 0; e < 8; e++){
      float ev = __expf(b2f((u16)av[e]));
      ao[e] = (short)f2b(ev);
      ssum += ev;
    }
    *(short8*)(As + ar * 40 + ac) = ao;
    *(short8*)(Bs + ar * 40 + ac) = *(const short8*)(BT + (size_t)ar * 4096 + k0 + ac);
    __syncthreads();
    short8 a0 = *(const short8*)(As + (wr +      lr) * 40 + kb * 8);
    short8 a1 = *(const short8*)(As + (wr + 16 + lr) * 40 + kb * 8);
    short8 b0 = *(const short8*)(Bs + (wc +      lr) * 40 + kb * 8);
    short8 b1 = *(const short8*)(Bs + (wc + 16 + lr) * 40 + kb * 8);
    acc[0][0] = __builtin_amdgcn_mfma_f32_16x16x32_bf16(a0, b0, acc[0][0], 0, 0, 0);
    acc[0][1] = __builtin_amdgcn_mfma_f32_16x16x32_bf16(a0, b1, acc[0][1], 0, 0, 0);
    acc[1][0] = __builtin_amdgcn_mfma_f32_16x16x32_bf16(a1, b0, acc[1][0], 0, 0, 0);
    acc[1][1] = __builtin_amdgcn_mfma_f32_16x16x32_bf16(a1, b1, acc[1][1], 0, 0, 0);
    __syncthreads();
  }
  ssum += __shfl_xor(ssum, 1);
  ssum += __shfl_xor(ssum, 2);
  if ((tid & 3) == 0) atomicAdd(sden + b * 512 + h * 64 + ar, ssum);
  #pragma unroll
  for (int mi = 0; mi < 2; mi++)
    #pragma unroll
    for (int ni = 0; ni < 2; ni++)
      #pragma unroll
      for (int j = 0; j < 4; j++){
        int row = wr + mi * 16 + kb * 4 + j;
        int col = wc + ni * 16 + lr;
        P[(size_t)z * 4096 + (size_t)row * 64 + col] = acc[mi][ni][j];
      }
}

// ---- kctxw: ctx[d][e] = (sum of 8 P splits)/sden[d] (bf16, in LDS), then
//      M_b[co][h*64+d] = sum_e Wout[co][h*64+e] * ctx[d][e]
__global__ __launch_bounds__(256)
void kctxw(const float* __restrict__ P, const float* __restrict__ sden,
           const u16* __restrict__ woutbf, u16* __restrict__ M)
{
  const int z = blockIdx.z;                  // bh
  const int b = z >> 3, h = z & 7;
  const int m0 = blockIdx.y * 64;
  const int tid = threadIdx.x;
  __shared__ u16 As[64 * 72];
  __shared__ u16 Bs[64 * 72];
  {
    int r = tid >> 2, c0 = (tid & 3) * 16;
    const u16* wsrc = woutbf + (size_t)(m0 + r) * 512 + h * 64 + c0;
    *(short8*)(As + r * 72 + c0)     = *(const short8*)(wsrc);
    *(short8*)(As + r * 72 + c0 + 8) = *(const short8*)(wsrc + 8);
    float rs = 1.f / sden[b * 512 + h * 64 + r];
    const float* p = P + (size_t)z * 32768 + (size_t)r * 64 + c0;
    #pragma unroll
    for (int e = 0; e < 16; e++){
      float s = 0.f;
      #pragma unroll
      for (int sp = 0; sp < 8; sp++) s += p[e + sp * 4096];
      Bs[r * 72 + c0 + e] = f2b(s * rs);
    }
  }
  __syncthreads();
  const int wid = tid >> 6, lane = tid & 63;
  const int wr = (wid >> 1) * 32, wc = (wid & 1) * 32;
  const int lr = lane & 15, kb = lane >> 4;
  f32x4 acc[2][2] = {};
  #pragma unroll
  for (int k0 = 0; k0 < 64; k0 += 32){
    short8 a0 = *(const short8*)(As + (wr +      lr) * 72 + k0 + kb * 8);
    short8 a1 = *(const short8*)(As + (wr + 16 + lr) * 72 + k0 + kb * 8);
    short8 b0 = *(const short8*)(Bs + (wc +      lr) * 72 + k0 + kb * 8);
    short8 b1 = *(const short8*)(Bs + (wc + 16 + lr) * 72 + k0 + kb * 8);
    acc[0][0] = __builtin_amdgcn_mfma_f32_16x16x32_bf16(a0, b0, acc[0][0], 0, 0, 0);
    acc[0][1] = __builtin_amdgcn_mfma_f32_16x16x32_bf16(a0, b1, acc[0][1], 0, 0, 0);
    acc[1][0] = __builtin_amdgcn_mfma_f32_16x16x32_bf16(a1, b0, acc[1][0], 0, 0, 0);
    acc[1][1] = __builtin_amdgcn_mfma_f32_16x16x32_bf16(a1, b1, acc[1][1], 0, 0, 0);
  }
  #pragma unroll
  for (int mi = 0; mi < 2; mi++)
    #pragma unroll
    for (int ni = 0; ni < 2; ni++)
      #pragma unroll
      for (int j = 0; j < 4; j++){
        int row = m0 + wr + mi * 16 + kb * 4 + j;
        int col = wc + ni * 16 + lr;
        M[(size_t)b * 262144 + (size_t)row * 512 + h * 64 + col] = f2b(acc[mi][ni][j]);
      }
}

// ---- fused rms2: out2T [n][c] bf16 -> d_out [c][p] f32, 32 px/block
__global__ __launch_bounds__(256)
void krms2(const u16* __restrict__ o2, const float* __restrict__ g,
           float* __restrict__ out){
  __shared__ u16 lt[32][514];
  __shared__ float invs[32];
  __shared__ float gl[512];
  int t = threadIdx.x;
  int pg0 = blockIdx.x * 32;
  int b = pg0 >> 12, p0 = pg0 & 4095;
  gl[t] = g[t] * SQRT512;
  gl[t + 256] = g[t + 256] * SQRT512;
  int px2 = t >> 3, c0 = (t & 7) * 8;
  const u16* src = o2 + (size_t)(pg0 + px2) * 512;
  float s = 0.f;
  #pragma unroll
  for (int j = 0; j < 8; j++){
    int c = c0 + j * 64;
    short8 v = *(const short8*)(src + c);
    *(short8*)&lt[px2][c] = v;
    #pragma unroll
    for (int e = 0; e < 8; e++){ float f = b2f((u16)v[e]); s += f * f; }
  }
  s += __shfl_xor(s, 1); s += __shfl_xor(s, 2); s += __shfl_xor(s, 4);
  if ((t & 7) == 0) invs[px2] = rsqrtf(s + 1e-12f);
  __syncthreads();
  int c2 = t >> 2, pxc = (t & 3) * 8;
  float ivv[8];
  #pragma unroll
  for (int e = 0; e < 8; e++) ivv[e] = invs[pxc + e];
  #pragma unroll
  for (int pass = 0; pass < 8; pass++){
    int c = c2 + pass * 64;
    float gf = gl[c];
    float* dst = out + ((size_t)(b * 512 + c)) * 4096 + p0 + pxc;
    #pragma unroll
    for (int q = 0; q < 2; q++){
      f32x4 o;
      #pragma unroll
      for (int e = 0; e < 4; e++){
        int pp = q * 4 + e;
        o[e] = b2f(lt[pxc + pp][c]) * ivv[pp] * gf;
      }
      *(f32x4*)(dst + q * 4) = o;
    }
  }
}

extern "C" void kernel_launch(void* const* d_in, const int* in_sizes, int n_in,
                              void* d_out, int out_size, void* d_ws, size_t ws_size,
                              hipStream_t stream)
{
  (void)in_sizes; (void)n_in; (void)out_size; (void)ws_size;
  const float* x    = (const float*)d_in[0];
  const float* g1   = (const float*)d_in[1];
  const float* wqkv = (const float*)d_in[2];
  const float* wout = (const float*)d_in[3];
  const float* bout = (const float*)d_in[4];
  const float* g2   = (const float*)d_in[5];
  float* out = (float*)d_out;
  char* ws = (char*)d_ws;

  u16*   xnT   = (u16*)(ws);                          // S1 (dead after gemm_qkv)
  float* P     = (float*)(ws);                        // S1+0, 8MB (after xnT dead)
  u16*   M     = (u16*)(ws + (size_t)8388608);        // S1+8M, 4MB
  u16*   qT    = (u16*)(ws + (size_t)33554432);       // S2
  u16*   kv    = (u16*)(ws + (size_t)67108864);       // S3 (dead after gemm_ctx)
  u16*   out2T = (u16*)(ws + (size_t)67108864);       // S3 (after kv dead)
  u16*   wbf   = (u16*)(ws + (size_t)134217728);      // E: wq+wkv bf16 (1.5MB)
  u16*   wkvbf = wbf + (size_t)512 * 512;
  u16*   woutbf= (u16*)(ws + (size_t)135790592);      // 512KB
  float* sden  = (float*)(ws + (size_t)136314880);    // 16KB

  // 1) weights->bf16 (g1 folded) + fused rms1 -> xnT + zero sden
  kprep<<<2048, 256, 0, stream>>>(wqkv, wout, g1, wbf, woutbf, x, xnT, sden);
  // 2) merged: kv (work 0-2047) + qT (work 2048-3071), XCD-swizzled
  gemm_qkv<<<3072, 256, 0, stream>>>(wkvbf, wbf, xnT, kv, qT);
  // 3) ctx split-K(8) partials (unnormalized exp(k); sden accumulated inline)
  gemm_ctx<<<dim3(1, 1, 512), 256, 0, stream>>>(kv, P, sden);
  // 4) reduce partials, normalize by sden, fold W_out: M_b = Wout_h @ ctx_bh
  kctxw<<<dim3(1, 8, 64), 256, 0, stream>>>(P, sden, woutbf, M);
  // 5) out2T = qT @ M_b^T + bias (128^2 tiles, 1024 work units, XCD-swizzled)
  gemm_out<<<1024, 256, 0, stream>>>(qT, M, out2T, bout);
  // 6) fused rms2 -> d_out [c][p] f32
  krms2<<<1024, 256, 0, stream>>>(out2T, g2, out);
}

// Round 16
// 177.939 us; speedup vs baseline: 1.0631x; 1.0631x over previous
//
#include <hip/hip_runtime.h>

// LinearAttention on MI355X — round 16 = round 13 (best, 181.5us; NO XCD
// swizzle — r15 showed it hurts here) + f32x4-vectorized kprep rms1 reads.
// ws: S1=0: xnT -> P(8MB) + M@+8M | S2=33.5M: qT | S3=67.1M: kv -> out2T
//     E=134217728: wbf(1.5M) | woutbf@135790592 | sden@136314880 (16KB)

typedef unsigned short u16;
typedef __attribute__((ext_vector_type(8))) short short8;
typedef __attribute__((ext_vector_type(4))) short short4_t;
typedef __attribute__((ext_vector_type(4))) float f32x4;

static constexpr size_t XN_B = (size_t)512 * 4096;
static constexpr size_t KV_B = (size_t)1024 * 4096;
static constexpr float SQRT512 = 22.62741699796952f;

typedef const __attribute__((address_space(1))) unsigned int gu32;
typedef __attribute__((address_space(3))) unsigned int lu32;

__device__ __forceinline__ float b2f(u16 u){
  union { unsigned u; float f; } x; x.u = ((unsigned)u) << 16; return x.f;
}
__device__ __forceinline__ u16 f2b(float f){
  union { float f; unsigned u; } x; x.f = f;
  unsigned r = x.u + 0x7FFFu + ((x.u >> 16) & 1u);   // RNE
  return (u16)(r >> 16);
}
__device__ __forceinline__ void gl16(const u16* g, u16* l){
  __builtin_amdgcn_global_load_lds((gu32*)g, (lu32*)l, 16, 0, 0);
}

// ---- kprep: blocks 0-1023 convert weights (g1 folded into wqkv; blocks 0-15
//      also zero sden); blocks 1024-2047 fused rms1 (x -> xnT [p][c] bf16)
//      rms1 reads are f32x4-vectorized: thread = 4 pixels x 16 channels.
__global__ __launch_bounds__(256)
void kprep(const float* __restrict__ wqkv, const float* __restrict__ wout,
           const float* __restrict__ g1, u16* __restrict__ dq, u16* __restrict__ dw,
           const float* __restrict__ x, u16* __restrict__ xnT,
           float* __restrict__ sden){
  __shared__ u16 lt[32][514];
  __shared__ float red4[256][4];
  __shared__ float invs[32];
  int bid = blockIdx.x;
  int t = threadIdx.x;
  if (bid < 1024){
    if (bid < 16) sden[bid * 256 + t] = 0.f;
    size_t i = ((size_t)bid * 256 + t) * 4;
    short4_t o;
    if (i < (size_t)786432){
      f32x4 v = *(const f32x4*)(wqkv + i);
      int c = (int)(i & 511);
      #pragma unroll
      for (int j = 0; j < 4; j++) o[j] = (short)f2b(v[j] * g1[c + j] * SQRT512);
      *(short4_t*)(dq + i) = o;
    } else {
      size_t off = i - 786432;
      f32x4 v = *(const f32x4*)(wout + off);
      #pragma unroll
      for (int j = 0; j < 4; j++) o[j] = (short)f2b(v[j]);
      *(short4_t*)(dw + off) = o;
    }
    return;
  }
  int pg0 = (bid - 1024) * 32;
  int b = pg0 >> 12, p0 = pg0 & 4095;
  int pxg = (t & 7) * 4;                 // pixel group base: 0,4,..,28
  int chunk = t >> 3;                    // 0..31 -> channels chunk*16..+16
  const float* xp = x + (size_t)b * XN_B + p0 + pxg;
  f32x4 s = {0.f, 0.f, 0.f, 0.f};
  #pragma unroll 4
  for (int c = chunk * 16; c < chunk * 16 + 16; ++c){
    f32x4 v = *(const f32x4*)(xp + (size_t)c * 4096);
    #pragma unroll
    for (int j = 0; j < 4; j++){
      lt[pxg + j][c] = f2b(v[j]);
      s[j] += v[j] * v[j];
    }
  }
  *(f32x4*)red4[t] = s;
  __syncthreads();
  if (t < 32){
    int pg = t >> 2, pe = t & 3;         // pixel t = (group pg, elem pe)
    float sum = 0.f;
    #pragma unroll
    for (int ch = 0; ch < 32; ch++) sum += red4[ch * 8 + pg][pe];
    invs[t] = rsqrtf(sum + 1e-12f);
  }
  __syncthreads();
  int px2 = t >> 3, c0 = (t & 7) * 8;
  float iv = invs[px2];
  u16* dst = xnT + (size_t)(pg0 + px2) * 512;
  #pragma unroll
  for (int j = 0; j < 8; j++){
    int c = c0 + j * 64;
    short8 o;
    #pragma unroll
    for (int e = 0; e < 8; e++) o[e] = (short)f2b(b2f(lt[px2][c + e]) * iv);
    *(short8*)(dst + c) = o;
  }
}

// ---- merged qT + kv GEMM. 128^2 tile, BK=64 dbuf, counted vmcnt(8), XOR
// swizzle (round-5 loop). Blocks 0-2047: kv_b = Wkv @ xn_b. Blocks 2048-3071:
// qT = softmax_d(xnT @ Wq^T)/8 (SMAX epilogue on the 64x64 wave quadrant).
__global__ __launch_bounds__(256)
void gemm_qkv(const u16* __restrict__ Wkv, const u16* __restrict__ wq,
              const u16* __restrict__ xnT, u16* __restrict__ kvb,
              u16* __restrict__ qT)
{
  constexpr int NT = 8;                 // K=512 / BK=64
  const int bid = blockIdx.x;
  const u16* A; const u16* BT; u16* C;
  int m0, n0; size_t ldc; bool smax;
  if (bid < 2048){
    int ntile = bid & 31, mtile = (bid >> 5) & 7, z = bid >> 8;
    A = Wkv; BT = xnT + (size_t)z * XN_B; C = kvb + (size_t)z * KV_B;
    m0 = mtile * 128; n0 = ntile * 128; ldc = 4096; smax = false;
  } else {
    int idx = bid - 2048;
    int ntile = idx & 3, mtile = idx >> 2;
    A = xnT; BT = wq; C = qT;
    m0 = mtile * 128; n0 = ntile * 128; ldc = 512; smax = true;
  }
  __shared__ u16 As[2][128 * 64];
  __shared__ u16 Bs[2][128 * 64];
  const int tid = threadIdx.x;
  const int srow0 = tid >> 3;           // 32 rows per staging group
  const int schunk = tid & 7;           // 16B chunk slot within 128B row
  const int lane = tid & 63, wid = tid >> 6;
  const int wr = (wid >> 1) * 64, wc = (wid & 1) * 64;
  const int fr = lane & 15, fq = lane >> 4;
  f32x4 acc[4][4] = {};

  auto STAGE = [&](int s, int t){
    const int k0 = t * 64;
    #pragma unroll
    for (int r = 0; r < 4; r++){
      int row = r * 32 + srow0;
      int gj = (schunk ^ (row & 7)) * 8;
      gl16(A  + (size_t)(m0 + row) * 512 + k0 + gj, &As[s][0] + r * 2048 + tid * 8);
      gl16(BT + (size_t)(n0 + row) * 512 + k0 + gj, &Bs[s][0] + r * 2048 + tid * 8);
    }
  };

  STAGE(0, 0);
  int cur = 0;
  for (int t = 0; t < NT; t++){
    if (t + 1 < NT){
      STAGE(cur ^ 1, t + 1);
      asm volatile("s_waitcnt vmcnt(8)" ::: "memory");
    } else {
      asm volatile("s_waitcnt vmcnt(0)" ::: "memory");
    }
    __builtin_amdgcn_s_barrier();
    __builtin_amdgcn_sched_barrier(0);
    #pragma unroll
    for (int ks = 0; ks < 2; ks++){
      short8 a[4], b[4];
      #pragma unroll
      for (int i = 0; i < 4; i++){
        int ra = wr + i * 16 + fr;
        a[i] = *(const short8*)(&As[cur][0] + ra * 64 + ((ks * 4 + fq) ^ (ra & 7)) * 8);
        int rb = wc + i * 16 + fr;
        b[i] = *(const short8*)(&Bs[cur][0] + rb * 64 + ((ks * 4 + fq) ^ (rb & 7)) * 8);
      }
      #pragma unroll
      for (int i = 0; i < 4; i++)
        #pragma unroll
        for (int j = 0; j < 4; j++)
          acc[i][j] = __builtin_amdgcn_mfma_f32_16x16x32_bf16(a[i], b[j], acc[i][j], 0, 0, 0);
    }
    __builtin_amdgcn_sched_barrier(0);
    __builtin_amdgcn_s_barrier();
    cur ^= 1;
  }

  if (smax){
    // softmax over each row's 64-col quadrant (= one head), then /8
    #pragma unroll
    for (int i = 0; i < 4; i++)
      #pragma unroll
      for (int e = 0; e < 4; e++){
        float mx = fmaxf(fmaxf(acc[i][0][e], acc[i][1][e]),
                         fmaxf(acc[i][2][e], acc[i][3][e]));
        mx = fmaxf(mx, __shfl_xor(mx, 1));
        mx = fmaxf(mx, __shfl_xor(mx, 2));
        mx = fmaxf(mx, __shfl_xor(mx, 4));
        mx = fmaxf(mx, __shfl_xor(mx, 8));
        float p0 = __expf(acc[i][0][e] - mx);
        float p1 = __expf(acc[i][1][e] - mx);
        float p2 = __expf(acc[i][2][e] - mx);
        float p3 = __expf(acc[i][3][e] - mx);
        float s = p0 + p1 + p2 + p3;
        s += __shfl_xor(s, 1);
        s += __shfl_xor(s, 2);
        s += __shfl_xor(s, 4);
        s += __shfl_xor(s, 8);
        float r = 1.f / (s * 8.0f);    // SCALE = sqrt(64) = 8
        acc[i][0][e] = p0 * r; acc[i][1][e] = p1 * r;
        acc[i][2][e] = p2 * r; acc[i][3][e] = p3 * r;
      }
  }
  #pragma unroll
  for (int i = 0; i < 4; i++)
    #pragma unroll
    for (int j = 0; j < 4; j++)
      #pragma unroll
      for (int e = 0; e < 4; e++){
        int row = m0 + wr + i * 16 + fq * 4 + e;
        int col = n0 + wc + j * 16 + fr;
        C[(size_t)row * ldc + col] = f2b(acc[i][j][e]);
      }
}

// ---- out2 GEMM: out2T_b = qT_b @ M_b^T + bias (M=4096,N=512,K=512/batch).
// Same 128^2/BK=64 structure, 1024 blocks.
__global__ __launch_bounds__(256)
void gemm_out(const u16* __restrict__ qT, const u16* __restrict__ Mb,
              u16* __restrict__ out2T, const float* __restrict__ bias)
{
  constexpr int NT = 8;
  const int z = blockIdx.z;
  const u16* A  = qT + (size_t)z * 4096 * 512;
  const u16* BT = Mb + (size_t)z * 262144;
  u16* C = out2T + (size_t)z * 4096 * 512;
  const int m0 = blockIdx.y * 128, n0 = blockIdx.x * 128;
  __shared__ u16 As[2][128 * 64];
  __shared__ u16 Bs[2][128 * 64];
  const int tid = threadIdx.x;
  const int srow0 = tid >> 3;
  const int schunk = tid & 7;
  const int lane = tid & 63, wid = tid >> 6;
  const int wr = (wid >> 1) * 64, wc = (wid & 1) * 64;
  const int fr = lane & 15, fq = lane >> 4;
  f32x4 acc[4][4] = {};

  auto STAGE = [&](int s, int t){
    const int k0 = t * 64;
    #pragma unroll
    for (int r = 0; r < 4; r++){
      int row = r * 32 + srow0;
      int gj = (schunk ^ (row & 7)) * 8;
      gl16(A  + (size_t)(m0 + row) * 512 + k0 + gj, &As[s][0] + r * 2048 + tid * 8);
      gl16(BT + (size_t)(n0 + row) * 512 + k0 + gj, &Bs[s][0] + r * 2048 + tid * 8);
    }
  };

  STAGE(0, 0);
  int cur = 0;
  for (int t = 0; t < NT; t++){
    if (t + 1 < NT){
      STAGE(cur ^ 1, t + 1);
      asm volatile("s_waitcnt vmcnt(8)" ::: "memory");
    } else {
      asm volatile("s_waitcnt vmcnt(0)" ::: "memory");
    }
    __builtin_amdgcn_s_barrier();
    __builtin_amdgcn_sched_barrier(0);
    #pragma unroll
    for (int ks = 0; ks < 2; ks++){
      short8 a[4], b[4];
      #pragma unroll
      for (int i = 0; i < 4; i++){
        int ra = wr + i * 16 + fr;
        a[i] = *(const short8*)(&As[cur][0] + ra * 64 + ((ks * 4 + fq) ^ (ra & 7)) * 8);
        int rb = wc + i * 16 + fr;
        b[i] = *(const short8*)(&Bs[cur][0] + rb * 64 + ((ks * 4 + fq) ^ (rb & 7)) * 8);
      }
      #pragma unroll
      for (int i = 0; i < 4; i++)
        #pragma unroll
        for (int j = 0; j < 4; j++)
          acc[i][j] = __builtin_amdgcn_mfma_f32_16x16x32_bf16(a[i], b[j], acc[i][j], 0, 0, 0);
    }
    __builtin_amdgcn_sched_barrier(0);
    __builtin_amdgcn_s_barrier();
    cur ^= 1;
  }

  #pragma unroll
  for (int i = 0; i < 4; i++)
    #pragma unroll
    for (int j = 0; j < 4; j++)
      #pragma unroll
      for (int e = 0; e < 4; e++){
        int row = m0 + wr + i * 16 + fq * 4 + e;
        int col = n0 + wc + j * 16 + fr;
        C[(size_t)row * 512 + col] = f2b(acc[i][j][e] + bias[col]);
      }
}

// ---- ctx split-K(8) partials: P[z=bh*8+s][d][e] f32. Stages UNNORMALIZED
// exp(k); accumulates the row expsum during staging -> atomicAdd into sden.
__global__ __launch_bounds__(256)
void gemm_ctx(const u16* __restrict__ kv, float* __restrict__ P,
              float* __restrict__ sden)
{
  constexpr int K = 512;                     // 4096 / 8 splits
  const int z = blockIdx.z;
  const int tid = threadIdx.x;
  const int ar = tid >> 2, ac = (tid & 3) * 8;
  int bh = z >> 3, sp = z & 7, b = bh >> 3, h = bh & 7;
  const u16* A  = kv + (size_t)b * KV_B + (size_t)(h * 64) * 4096 + sp * 512;
  const u16* BT = kv + (size_t)b * KV_B + (size_t)(512 + h * 64) * 4096 + sp * 512;
  __shared__ u16 As[64 * 40];
  __shared__ u16 Bs[64 * 40];
  const int wid = tid >> 6, lane = tid & 63;
  const int wr = (wid >> 1) * 32, wc = (wid & 1) * 32;
  const int lr = lane & 15, kb = lane >> 4;
  f32x4 acc[2][2] = {};
  float ssum = 0.f;
  for (int k0 = 0; k0 < K; k0 += 32){
    short8 av = *(const short8*)(A + (size_t)ar * 4096 + k0 + ac);
    short8 ao;
    #pragma unroll
    for (int e = 0; e < 8; e++){
      float ev = __expf(b2f((u16)av[e]));
      ao[e] = (short)f2b(ev);
      ssum += ev;
    }
    *(short8*)(As + ar * 40 + ac) = ao;
    *(short8*)(Bs + ar * 40 + ac) = *(const short8*)(BT + (size_t)ar * 4096 + k0 + ac);
    __syncthreads();
    short8 a0 = *(const short8*)(As + (wr +      lr) * 40 + kb * 8);
    short8 a1 = *(const short8*)(As + (wr + 16 + lr) * 40 + kb * 8);
    short8 b0 = *(const short8*)(Bs + (wc +      lr) * 40 + kb * 8);
    short8 b1 = *(const short8*)(Bs + (wc + 16 + lr) * 40 + kb * 8);
    acc[0][0] = __builtin_amdgcn_mfma_f32_16x16x32_bf16(a0, b0, acc[0][0], 0, 0, 0);
    acc[0][1] = __builtin_amdgcn_mfma_f32_16x16x32_bf16(a0, b1, acc[0][1], 0, 0, 0);
    acc[1][0] = __builtin_amdgcn_mfma_f32_16x16x32_bf16(a1, b0, acc[1][0], 0, 0, 0);
    acc[1][1] = __builtin_amdgcn_mfma_f32_16x16x32_bf16(a1, b1, acc[1][1], 0, 0, 0);
    __syncthreads();
  }
  ssum += __shfl_xor(ssum, 1);
  ssum += __shfl_xor(ssum, 2);
  if ((tid & 3) == 0) atomicAdd(sden + b * 512 + h * 64 + ar, ssum);
  #pragma unroll
  for (int mi = 0; mi < 2; mi++)
    #pragma unroll
    for (int ni = 0; ni < 2; ni++)
      #pragma unroll
      for (int j = 0; j < 4; j++){
        int row = wr + mi * 16 + kb * 4 + j;
        int col = wc + ni * 16 + lr;
        P[(size_t)z * 4096 + (size_t)row * 64 + col] = acc[mi][ni][j];
      }
}

// ---- kctxw: ctx[d][e] = (sum of 8 P splits)/sden[d] (bf16, in LDS), then
//      M_b[co][h*64+d] = sum_e Wout[co][h*64+e] * ctx[d][e]
__global__ __launch_bounds__(256)
void kctxw(const float* __restrict__ P, const float* __restrict__ sden,
           const u16* __restrict__ woutbf, u16* __restrict__ M)
{
  const int z = blockIdx.z;                  // bh
  const int b = z >> 3, h = z & 7;
  const int m0 = blockIdx.y * 64;
  const int tid = threadIdx.x;
  __shared__ u16 As[64 * 72];
  __shared__ u16 Bs[64 * 72];
  {
    int r = tid >> 2, c0 = (tid & 3) * 16;
    const u16* wsrc = woutbf + (size_t)(m0 + r) * 512 + h * 64 + c0;
    *(short8*)(As + r * 72 + c0)     = *(const short8*)(wsrc);
    *(short8*)(As + r * 72 + c0 + 8) = *(const short8*)(wsrc + 8);
    float rs = 1.f / sden[b * 512 + h * 64 + r];
    const float* p = P + (size_t)z * 32768 + (size_t)r * 64 + c0;
    #pragma unroll
    for (int e = 0; e < 16; e++){
      float s = 0.f;
      #pragma unroll
      for (int sp = 0; sp < 8; sp++) s += p[e + sp * 4096];
      Bs[r * 72 + c0 + e] = f2b(s * rs);
    }
  }
  __syncthreads();
  const int wid = tid >> 6, lane = tid & 63;
  const int wr = (wid >> 1) * 32, wc = (wid & 1) * 32;
  const int lr = lane & 15, kb = lane >> 4;
  f32x4 acc[2][2] = {};
  #pragma unroll
  for (int k0 = 0; k0 < 64; k0 += 32){
    short8 a0 = *(const short8*)(As + (wr +      lr) * 72 + k0 + kb * 8);
    short8 a1 = *(const short8*)(As + (wr + 16 + lr) * 72 + k0 + kb * 8);
    short8 b0 = *(const short8*)(Bs + (wc +      lr) * 72 + k0 + kb * 8);
    short8 b1 = *(const short8*)(Bs + (wc + 16 + lr) * 72 + k0 + kb * 8);
    acc[0][0] = __builtin_amdgcn_mfma_f32_16x16x32_bf16(a0, b0, acc[0][0], 0, 0, 0);
    acc[0][1] = __builtin_amdgcn_mfma_f32_16x16x32_bf16(a0, b1, acc[0][1], 0, 0, 0);
    acc[1][0] = __builtin_amdgcn_mfma_f32_16x16x32_bf16(a1, b0, acc[1][0], 0, 0, 0);
    acc[1][1] = __builtin_amdgcn_mfma_f32_16x16x32_bf16(a1, b1, acc[1][1], 0, 0, 0);
  }
  #pragma unroll
  for (int mi = 0; mi < 2; mi++)
    #pragma unroll
    for (int ni = 0; ni < 2; ni++)
      #pragma unroll
      for (int j = 0; j < 4; j++){
        int row = m0 + wr + mi * 16 + kb * 4 + j;
        int col = wc + ni * 16 + lr;
        M[(size_t)b * 262144 + (size_t)row * 512 + h * 64 + col] = f2b(acc[mi][ni][j]);
      }
}

// ---- fused rms2: out2T [n][c] bf16 -> d_out [c][p] f32, 32 px/block
__global__ __launch_bounds__(256)
void krms2(const u16* __restrict__ o2, const float* __restrict__ g,
           float* __restrict__ out){
  __shared__ u16 lt[32][514];
  __shared__ float invs[32];
  __shared__ float gl[512];
  int t = threadIdx.x;
  int pg0 = blockIdx.x * 32;
  int b = pg0 >> 12, p0 = pg0 & 4095;
  gl[t] = g[t] * SQRT512;
  gl[t + 256] = g[t + 256] * SQRT512;
  int px2 = t >> 3, c0 = (t & 7) * 8;
  const u16* src = o2 + (size_t)(pg0 + px2) * 512;
  float s = 0.f;
  #pragma unroll
  for (int j = 0; j < 8; j++){
    int c = c0 + j * 64;
    short8 v = *(const short8*)(src + c);
    *(short8*)&lt[px2][c] = v;
    #pragma unroll
    for (int e = 0; e < 8; e++){ float f = b2f((u16)v[e]); s += f * f; }
  }
  s += __shfl_xor(s, 1); s += __shfl_xor(s, 2); s += __shfl_xor(s, 4);
  if ((t & 7) == 0) invs[px2] = rsqrtf(s + 1e-12f);
  __syncthreads();
  int c2 = t >> 2, pxc = (t & 3) * 8;
  float ivv[8];
  #pragma unroll
  for (int e = 0; e < 8; e++) ivv[e] = invs[pxc + e];
  #pragma unroll
  for (int pass = 0; pass < 8; pass++){
    int c = c2 + pass * 64;
    float gf = gl[c];
    float* dst = out + ((size_t)(b * 512 + c)) * 4096 + p0 + pxc;
    #pragma unroll
    for (int q = 0; q < 2; q++){
      f32x4 o;
      #pragma unroll
      for (int e = 0; e < 4; e++){
        int pp = q * 4 + e;
        o[e] = b2f(lt[pxc + pp][c]) * ivv[pp] * gf;
      }
      *(f32x4*)(dst + q * 4) = o;
    }
  }
}

extern "C" void kernel_launch(void* const* d_in, const int* in_sizes, int n_in,
                              void* d_out, int out_size, void* d_ws, size_t ws_size,
                              hipStream_t stream)
{
  (void)in_sizes; (void)n_in; (void)out_size; (void)ws_size;
  const float* x    = (const float*)d_in[0];
  const float* g1   = (const float*)d_in[1];
  const float* wqkv = (const float*)d_in[2];
  const float* wout = (const float*)d_in[3];
  const float* bout = (const float*)d_in[4];
  const float* g2   = (const float*)d_in[5];
  float* out = (float*)d_out;
  char* ws = (char*)d_ws;

  u16*   xnT   = (u16*)(ws);                          // S1 (dead after gemm_qkv)
  float* P     = (float*)(ws);                        // S1+0, 8MB (after xnT dead)
  u16*   M     = (u16*)(ws + (size_t)8388608);        // S1+8M, 4MB
  u16*   qT    = (u16*)(ws + (size_t)33554432);       // S2
  u16*   kv    = (u16*)(ws + (size_t)67108864);       // S3 (dead after gemm_ctx)
  u16*   out2T = (u16*)(ws + (size_t)67108864);       // S3 (after kv dead)
  u16*   wbf   = (u16*)(ws + (size_t)134217728);      // E: wq+wkv bf16 (1.5MB)
  u16*   wkvbf = wbf + (size_t)512 * 512;
  u16*   woutbf= (u16*)(ws + (size_t)135790592);      // 512KB
  float* sden  = (float*)(ws + (size_t)136314880);    // 16KB

  // 1) weights->bf16 (g1 folded) + fused rms1 (vectorized) -> xnT + zero sden
  kprep<<<2048, 256, 0, stream>>>(wqkv, wout, g1, wbf, woutbf, x, xnT, sden);
  // 2) merged: kv_b = Wkv @ xn_b (blocks 0-2047) + qT = softmax_d(xnT@Wq^T)/8
  //    (blocks 2048-3071)
  gemm_qkv<<<3072, 256, 0, stream>>>(wkvbf, wbf, xnT, kv, qT);
  // 3) ctx split-K(8) partials (unnormalized exp(k); sden accumulated inline)
  gemm_ctx<<<dim3(1, 1, 512), 256, 0, stream>>>(kv, P, sden);
  // 4) reduce partials, normalize by sden, fold W_out: M_b = Wout_h @ ctx_bh
  kctxw<<<dim3(1, 8, 64), 256, 0, stream>>>(P, sden, woutbf, M);
  // 5) out2T = qT @ M_b^T + bias (128^2 tiles, 1024 blocks)
  gemm_out<<<dim3(4, 32, 8), 256, 0, stream>>>(qT, M, out2T, bout);
  // 6) fused rms2 -> d_out [c][p] f32
  krms2<<<1024, 256, 0, stream>>>(out2T, g2, out);
}

// Round 17
// 164.232 us; speedup vs baseline: 1.1519x; 1.0835x over previous
//
#include <hip/hip_runtime.h>

// LinearAttention on MI355X — round 17 = round 16 + gemm_out⊕rms2 fusion:
//  gemm_outrms: 128x512 tile (full channel rows), 512 thr / 8 waves, BK=32
//  dbuf vmcnt(5), chunk-XOR swizzle; epilogue does bias + row-sumsq (shfl+LDS)
//  + rms-normalize (f32) + LDS transpose + direct f32 [c][p] stores.
//  out2T buffer and krms2 dispatch DELETED (67MB round-trip removed).
// ws: S1=0: xnT -> P(8MB) + M@+8M | S2=33.5M: qT | S3=67.1M: kv
//     E=134217728: wbf(1.5M) | woutbf@135790592 | sden@136314880 (16KB)

typedef unsigned short u16;
typedef __attribute__((ext_vector_type(8))) short short8;
typedef __attribute__((ext_vector_type(4))) short short4_t;
typedef __attribute__((ext_vector_type(4))) float f32x4;

static constexpr size_t XN_B = (size_t)512 * 4096;
static constexpr size_t KV_B = (size_t)1024 * 4096;
static constexpr float SQRT512 = 22.62741699796952f;

typedef const __attribute__((address_space(1))) unsigned int gu32;
typedef __attribute__((address_space(3))) unsigned int lu32;

__device__ __forceinline__ float b2f(u16 u){
  union { unsigned u; float f; } x; x.u = ((unsigned)u) << 16; return x.f;
}
__device__ __forceinline__ u16 f2b(float f){
  union { float f; unsigned u; } x; x.f = f;
  unsigned r = x.u + 0x7FFFu + ((x.u >> 16) & 1u);   // RNE
  return (u16)(r >> 16);
}
__device__ __forceinline__ void gl16(const u16* g, u16* l){
  __builtin_amdgcn_global_load_lds((gu32*)g, (lu32*)l, 16, 0, 0);
}

// ---- kprep: blocks 0-1023 convert weights (g1 folded into wqkv; blocks 0-15
//      also zero sden); blocks 1024-2047 fused rms1, f32x4-vectorized
__global__ __launch_bounds__(256)
void kprep(const float* __restrict__ wqkv, const float* __restrict__ wout,
           const float* __restrict__ g1, u16* __restrict__ dq, u16* __restrict__ dw,
           const float* __restrict__ x, u16* __restrict__ xnT,
           float* __restrict__ sden){
  __shared__ u16 lt[32][514];
  __shared__ float red4[256][4];
  __shared__ float invs[32];
  int bid = blockIdx.x;
  int t = threadIdx.x;
  if (bid < 1024){
    if (bid < 16) sden[bid * 256 + t] = 0.f;
    size_t i = ((size_t)bid * 256 + t) * 4;
    short4_t o;
    if (i < (size_t)786432){
      f32x4 v = *(const f32x4*)(wqkv + i);
      int c = (int)(i & 511);
      #pragma unroll
      for (int j = 0; j < 4; j++) o[j] = (short)f2b(v[j] * g1[c + j] * SQRT512);
      *(short4_t*)(dq + i) = o;
    } else {
      size_t off = i - 786432;
      f32x4 v = *(const f32x4*)(wout + off);
      #pragma unroll
      for (int j = 0; j < 4; j++) o[j] = (short)f2b(v[j]);
      *(short4_t*)(dw + off) = o;
    }
    return;
  }
  int pg0 = (bid - 1024) * 32;
  int b = pg0 >> 12, p0 = pg0 & 4095;
  int pxg = (t & 7) * 4;
  int chunk = t >> 3;
  const float* xp = x + (size_t)b * XN_B + p0 + pxg;
  f32x4 s = {0.f, 0.f, 0.f, 0.f};
  #pragma unroll 4
  for (int c = chunk * 16; c < chunk * 16 + 16; ++c){
    f32x4 v = *(const f32x4*)(xp + (size_t)c * 4096);
    #pragma unroll
    for (int j = 0; j < 4; j++){
      lt[pxg + j][c] = f2b(v[j]);
      s[j] += v[j] * v[j];
    }
  }
  *(f32x4*)red4[t] = s;
  __syncthreads();
  if (t < 32){
    int pg = t >> 2, pe = t & 3;
    float sum = 0.f;
    #pragma unroll
    for (int ch = 0; ch < 32; ch++) sum += red4[ch * 8 + pg][pe];
    invs[t] = rsqrtf(sum + 1e-12f);
  }
  __syncthreads();
  int px2 = t >> 3, c0 = (t & 7) * 8;
  float iv = invs[px2];
  u16* dst = xnT + (size_t)(pg0 + px2) * 512;
  #pragma unroll
  for (int j = 0; j < 8; j++){
    int c = c0 + j * 64;
    short8 o;
    #pragma unroll
    for (int e = 0; e < 8; e++) o[e] = (short)f2b(b2f(lt[px2][c + e]) * iv);
    *(short8*)(dst + c) = o;
  }
}

// ---- merged qT + kv GEMM (unchanged from r16). 128^2 tile, BK=64 dbuf,
// vmcnt(8), XOR swizzle. Blocks 0-2047: kv. Blocks 2048-3071: qT + SMAX.
__global__ __launch_bounds__(256)
void gemm_qkv(const u16* __restrict__ Wkv, const u16* __restrict__ wq,
              const u16* __restrict__ xnT, u16* __restrict__ kvb,
              u16* __restrict__ qT)
{
  constexpr int NT = 8;
  const int bid = blockIdx.x;
  const u16* A; const u16* BT; u16* C;
  int m0, n0; size_t ldc; bool smax;
  if (bid < 2048){
    int ntile = bid & 31, mtile = (bid >> 5) & 7, z = bid >> 8;
    A = Wkv; BT = xnT + (size_t)z * XN_B; C = kvb + (size_t)z * KV_B;
    m0 = mtile * 128; n0 = ntile * 128; ldc = 4096; smax = false;
  } else {
    int idx = bid - 2048;
    int ntile = idx & 3, mtile = idx >> 2;
    A = xnT; BT = wq; C = qT;
    m0 = mtile * 128; n0 = ntile * 128; ldc = 512; smax = true;
  }
  __shared__ u16 As[2][128 * 64];
  __shared__ u16 Bs[2][128 * 64];
  const int tid = threadIdx.x;
  const int srow0 = tid >> 3;
  const int schunk = tid & 7;
  const int lane = tid & 63, wid = tid >> 6;
  const int wr = (wid >> 1) * 64, wc = (wid & 1) * 64;
  const int fr = lane & 15, fq = lane >> 4;
  f32x4 acc[4][4] = {};

  auto STAGE = [&](int s, int t){
    const int k0 = t * 64;
    #pragma unroll
    for (int r = 0; r < 4; r++){
      int row = r * 32 + srow0;
      int gj = (schunk ^ (row & 7)) * 8;
      gl16(A  + (size_t)(m0 + row) * 512 + k0 + gj, &As[s][0] + r * 2048 + tid * 8);
      gl16(BT + (size_t)(n0 + row) * 512 + k0 + gj, &Bs[s][0] + r * 2048 + tid * 8);
    }
  };

  STAGE(0, 0);
  int cur = 0;
  for (int t = 0; t < NT; t++){
    if (t + 1 < NT){
      STAGE(cur ^ 1, t + 1);
      asm volatile("s_waitcnt vmcnt(8)" ::: "memory");
    } else {
      asm volatile("s_waitcnt vmcnt(0)" ::: "memory");
    }
    __builtin_amdgcn_s_barrier();
    __builtin_amdgcn_sched_barrier(0);
    #pragma unroll
    for (int ks = 0; ks < 2; ks++){
      short8 a[4], b[4];
      #pragma unroll
      for (int i = 0; i < 4; i++){
        int ra = wr + i * 16 + fr;
        a[i] = *(const short8*)(&As[cur][0] + ra * 64 + ((ks * 4 + fq) ^ (ra & 7)) * 8);
        int rb = wc + i * 16 + fr;
        b[i] = *(const short8*)(&Bs[cur][0] + rb * 64 + ((ks * 4 + fq) ^ (rb & 7)) * 8);
      }
      #pragma unroll
      for (int i = 0; i < 4; i++)
        #pragma unroll
        for (int j = 0; j < 4; j++)
          acc[i][j] = __builtin_amdgcn_mfma_f32_16x16x32_bf16(a[i], b[j], acc[i][j], 0, 0, 0);
    }
    __builtin_amdgcn_sched_barrier(0);
    __builtin_amdgcn_s_barrier();
    cur ^= 1;
  }

  if (smax){
    #pragma unroll
    for (int i = 0; i < 4; i++)
      #pragma unroll
      for (int e = 0; e < 4; e++){
        float mx = fmaxf(fmaxf(acc[i][0][e], acc[i][1][e]),
                         fmaxf(acc[i][2][e], acc[i][3][e]));
        mx = fmaxf(mx, __shfl_xor(mx, 1));
        mx = fmaxf(mx, __shfl_xor(mx, 2));
        mx = fmaxf(mx, __shfl_xor(mx, 4));
        mx = fmaxf(mx, __shfl_xor(mx, 8));
        float p0 = __expf(acc[i][0][e] - mx);
        float p1 = __expf(acc[i][1][e] - mx);
        float p2 = __expf(acc[i][2][e] - mx);
        float p3 = __expf(acc[i][3][e] - mx);
        float s = p0 + p1 + p2 + p3;
        s += __shfl_xor(s, 1);
        s += __shfl_xor(s, 2);
        s += __shfl_xor(s, 4);
        s += __shfl_xor(s, 8);
        float r = 1.f / (s * 8.0f);
        acc[i][0][e] = p0 * r; acc[i][1][e] = p1 * r;
        acc[i][2][e] = p2 * r; acc[i][3][e] = p3 * r;
      }
  }
  #pragma unroll
  for (int i = 0; i < 4; i++)
    #pragma unroll
    for (int j = 0; j < 4; j++)
      #pragma unroll
      for (int e = 0; e < 4; e++){
        int row = m0 + wr + i * 16 + fq * 4 + e;
        int col = n0 + wc + j * 16 + fr;
        C[(size_t)row * ldc + col] = f2b(acc[i][j][e]);
      }
}

// ---- fused out2 GEMM + rms2: per block a 128(pixel)x512(channel) tile.
// out2 = qT_b @ M_b^T + bias; then rms over the full row (in f32) and
// transposed f32 store to d_out [c][p]. out2T never materialized.
__global__ __launch_bounds__(512)
void gemm_outrms(const u16* __restrict__ qT, const u16* __restrict__ Mb,
                 const float* __restrict__ bias, const float* __restrict__ g2,
                 float* __restrict__ out)
{
  constexpr int NT = 16;                 // K=512 / BK=32
  const int mt = blockIdx.x, z = blockIdx.y;
  const u16* A  = qT + (size_t)z * 4096 * 512;   // [4096 px][512]
  const u16* BT = Mb + (size_t)z * 262144;       // [512 ch][512]
  const int m0 = mt * 128;

  __shared__ char smem[84480] __attribute__((aligned(16)));
  u16*   As    = (u16*)smem;                 // [2][128*32] = 16384 B
  u16*   Bs    = (u16*)(smem + 16384);       // [2][512*32] = 65536 B
  float* trans = (float*)smem;               // [512][40]   = 81920 B (epilogue)
  float* rsum  = (float*)(smem + 81920);     // [128][4]
  float* invr  = (float*)(smem + 83968);     // [128]

  const int tid = threadIdx.x;
  const int lane = tid & 63, wid = tid >> 6;
  const int wr = (wid >> 2) * 64;            // 2 M-groups
  const int wc = (wid & 3) * 128;            // 4 N-groups
  const int fr = lane & 15, fq = lane >> 4;
  const int srow = tid >> 2, schunk = tid & 3;
  f32x4 acc[4][8] = {};

  auto STAGE = [&](int s, int t){
    const int k0 = t * 32;
    {   // A: 128 rows x 32k, one gl16/thread
      int gj = (schunk ^ ((srow >> 1) & 3)) * 8;
      gl16(A + (size_t)(m0 + srow) * 512 + k0 + gj, As + s * 4096 + tid * 8);
    }
    #pragma unroll
    for (int r = 0; r < 4; r++){   // B: 512 rows x 32k, 4 gl16/thread
      int row = r * 128 + srow;
      int gj = (schunk ^ ((row >> 1) & 3)) * 8;
      gl16(BT + (size_t)row * 512 + k0 + gj, Bs + s * 16384 + r * 4096 + tid * 8);
    }
  };

  STAGE(0, 0);
  int cur = 0;
  for (int t = 0; t < NT; t++){
    if (t + 1 < NT){
      STAGE(cur ^ 1, t + 1);
      asm volatile("s_waitcnt vmcnt(5)" ::: "memory");
    } else {
      asm volatile("s_waitcnt vmcnt(0)" ::: "memory");
    }
    __builtin_amdgcn_s_barrier();
    __builtin_amdgcn_sched_barrier(0);
    short8 a[4], b[8];
    #pragma unroll
    for (int i = 0; i < 4; i++){
      int ra = wr + i * 16 + fr;
      a[i] = *(const short8*)(As + cur * 4096 + ra * 32 + ((fq ^ ((ra >> 1) & 3)) * 8));
    }
    #pragma unroll
    for (int j = 0; j < 8; j++){
      int rb = wc + j * 16 + fr;
      b[j] = *(const short8*)(Bs + cur * 16384 + rb * 32 + ((fq ^ ((rb >> 1) & 3)) * 8));
    }
    #pragma unroll
    for (int i = 0; i < 4; i++)
      #pragma unroll
      for (int j = 0; j < 8; j++)
        acc[i][j] = __builtin_amdgcn_mfma_f32_16x16x32_bf16(a[i], b[j], acc[i][j], 0, 0, 0);
    __builtin_amdgcn_sched_barrier(0);
    __builtin_amdgcn_s_barrier();
    cur ^= 1;
  }

  // ---- epilogue: bias, row sumsq (full 512 cols), rms-normalize, transpose
  float bcol[8], gcol[8];
  #pragma unroll
  for (int j = 0; j < 8; j++){
    int col = wc + j * 16 + fr;
    bcol[j] = bias[col];
    gcol[j] = g2[col] * SQRT512;
  }
  #pragma unroll
  for (int i = 0; i < 4; i++)
    #pragma unroll
    for (int e = 0; e < 4; e++){
      float p = 0.f;
      #pragma unroll
      for (int j = 0; j < 8; j++){
        acc[i][j][e] += bcol[j];
        p += acc[i][j][e] * acc[i][j][e];
      }
      p += __shfl_xor(p, 1); p += __shfl_xor(p, 2);
      p += __shfl_xor(p, 4); p += __shfl_xor(p, 8);
      if (fr == 0) rsum[(wr + i * 16 + fq * 4 + e) * 4 + (wid & 3)] = p;
    }
  __syncthreads();
  if (tid < 128){
    float ss = rsum[tid * 4] + rsum[tid * 4 + 1] + rsum[tid * 4 + 2] + rsum[tid * 4 + 3];
    invr[tid] = rsqrtf(ss + 1e-12f);
  }
  __syncthreads();
  #pragma unroll
  for (int i = 0; i < 4; i++)
    #pragma unroll
    for (int e = 0; e < 4; e++){
      float iv = invr[wr + i * 16 + fq * 4 + e];
      #pragma unroll
      for (int j = 0; j < 8; j++)
        acc[i][j][e] *= iv * gcol[j];
    }
  // 4 transpose passes: rows [q*32, q*32+32) -> out[c][m0+q*32+..]
  const int myhalf = wid >> 2;
  const int cbase = tid >> 3, pi = (tid & 7) * 4;
  #pragma unroll
  for (int q = 0; q < 4; q++){
    __syncthreads();                         // previous pass reads done
    if (myhalf == (q >> 1)){
      #pragma unroll
      for (int ii = 0; ii < 2; ii++){
        const int i = (q & 1) * 2 + ii;
        const int ro = ii * 16 + fq * 4;
        #pragma unroll
        for (int j = 0; j < 8; j++){
          int col = wc + j * 16 + fr;
          *(f32x4*)&trans[col * 40 + ro] = acc[i][j];
        }
      }
    }
    __syncthreads();
    #pragma unroll
    for (int it = 0; it < 8; it++){
      int cc = it * 64 + cbase;
      f32x4 v = *(const f32x4*)&trans[cc * 40 + pi];
      *(f32x4*)(out + ((size_t)(z * 512 + cc)) * 4096 + m0 + q * 32 + pi) = v;
    }
  }
}

// ---- ctx split-K(8) partials: P[z=bh*8+s][d][e] f32. Stages UNNORMALIZED
// exp(k); accumulates the row expsum during staging -> atomicAdd into sden.
__global__ __launch_bounds__(256)
void gemm_ctx(const u16* __restrict__ kv, float* __restrict__ P,
              float* __restrict__ sden)
{
  constexpr int K = 512;                     // 4096 / 8 splits
  const int z = blockIdx.z;
  const int tid = threadIdx.x;
  const int ar = tid >> 2, ac = (tid & 3) * 8;
  int bh = z >> 3, sp = z & 7, b = bh >> 3, h = bh & 7;
  const u16* A  = kv + (size_t)b * KV_B + (size_t)(h * 64) * 4096 + sp * 512;
  const u16* BT = kv + (size_t)b * KV_B + (size_t)(512 + h * 64) * 4096 + sp * 512;
  __shared__ u16 As[64 * 40];
  __shared__ u16 Bs[64 * 40];
  const int wid = tid >> 6, lane = tid & 63;
  const int wr = (wid >> 1) * 32, wc = (wid & 1) * 32;
  const int lr = lane & 15, kb = lane >> 4;
  f32x4 acc[2][2] = {};
  float ssum = 0.f;
  for (int k0 = 0; k0 < K; k0 += 32){
    short8 av = *(const short8*)(A + (size_t)ar * 4096 + k0 + ac);
    short8 ao;
    #pragma unroll
    for (int e = 0; e < 8; e++){
      float ev = __expf(b2f((u16)av[e]));
      ao[e] = (short)f2b(ev);
      ssum += ev;
    }
    *(short8*)(As + ar * 40 + ac) = ao;
    *(short8*)(Bs + ar * 40 + ac) = *(const short8*)(BT + (size_t)ar * 4096 + k0 + ac);
    __syncthreads();
    short8 a0 = *(const short8*)(As + (wr +      lr) * 40 + kb * 8);
    short8 a1 = *(const short8*)(As + (wr + 16 + lr) * 40 + kb * 8);
    short8 b0 = *(const short8*)(Bs + (wc +      lr) * 40 + kb * 8);
    short8 b1 = *(const short8*)(Bs + (wc + 16 + lr) * 40 + kb * 8);
    acc[0][0] = __builtin_amdgcn_mfma_f32_16x16x32_bf16(a0, b0, acc[0][0], 0, 0, 0);
    acc[0][1] = __builtin_amdgcn_mfma_f32_16x16x32_bf16(a0, b1, acc[0][1], 0, 0, 0);
    acc[1][0] = __builtin_amdgcn_mfma_f32_16x16x32_bf16(a1, b0, acc[1][0], 0, 0, 0);
    acc[1][1] = __builtin_amdgcn_mfma_f32_16x16x32_bf16(a1, b1, acc[1][1], 0, 0, 0);
    __syncthreads();
  }
  ssum += __shfl_xor(ssum, 1);
  ssum += __shfl_xor(ssum, 2);
  if ((tid & 3) == 0) atomicAdd(sden + b * 512 + h * 64 + ar, ssum);
  #pragma unroll
  for (int mi = 0; mi < 2; mi++)
    #pragma unroll
    for (int ni = 0; ni < 2; ni++)
      #pragma unroll
      for (int j = 0; j < 4; j++){
        int row = wr + mi * 16 + kb * 4 + j;
        int col = wc + ni * 16 + lr;
        P[(size_t)z * 4096 + (size_t)row * 64 + col] = acc[mi][ni][j];
      }
}

// ---- kctxw: ctx[d][e] = (sum of 8 P splits)/sden[d] (bf16, in LDS), then
//      M_b[co][h*64+d] = sum_e Wout[co][h*64+e] * ctx[d][e]
__global__ __launch_bounds__(256)
void kctxw(const float* __restrict__ P, const float* __restrict__ sden,
           const u16* __restrict__ woutbf, u16* __restrict__ M)
{
  const int z = blockIdx.z;                  // bh
  const int b = z >> 3, h = z & 7;
  const int m0 = blockIdx.y * 64;
  const int tid = threadIdx.x;
  __shared__ u16 As[64 * 72];
  __shared__ u16 Bs[64 * 72];
  {
    int r = tid >> 2, c0 = (tid & 3) * 16;
    const u16* wsrc = woutbf + (size_t)(m0 + r) * 512 + h * 64 + c0;
    *(short8*)(As + r * 72 + c0)     = *(const short8*)(wsrc);
    *(short8*)(As + r * 72 + c0 + 8) = *(const short8*)(wsrc + 8);
    float rs = 1.f / sden[b * 512 + h * 64 + r];
    const float* p = P + (size_t)z * 32768 + (size_t)r * 64 + c0;
    #pragma unroll
    for (int e = 0; e < 16; e++){
      float s = 0.f;
      #pragma unroll
      for (int sp = 0; sp < 8; sp++) s += p[e + sp * 4096];
      Bs[r * 72 + c0 + e] = f2b(s * rs);
    }
  }
  __syncthreads();
  const int wid = tid >> 6, lane = tid & 63;
  const int wr = (wid >> 1) * 32, wc = (wid & 1) * 32;
  const int lr = lane & 15, kb = lane >> 4;
  f32x4 acc[2][2] = {};
  #pragma unroll
  for (int k0 = 0; k0 < 64; k0 += 32){
    short8 a0 = *(const short8*)(As + (wr +      lr) * 72 + k0 + kb * 8);
    short8 a1 = *(const short8*)(As + (wr + 16 + lr) * 72 + k0 + kb * 8);
    short8 b0 = *(const short8*)(Bs + (wc +      lr) * 72 + k0 + kb * 8);
    short8 b1 = *(const short8*)(Bs + (wc + 16 + lr) * 72 + k0 + kb * 8);
    acc[0][0] = __builtin_amdgcn_mfma_f32_16x16x32_bf16(a0, b0, acc[0][0], 0, 0, 0);
    acc[0][1] = __builtin_amdgcn_mfma_f32_16x16x32_bf16(a0, b1, acc[0][1], 0, 0, 0);
    acc[1][0] = __builtin_amdgcn_mfma_f32_16x16x32_bf16(a1, b0, acc[1][0], 0, 0, 0);
    acc[1][1] = __builtin_amdgcn_mfma_f32_16x16x32_bf16(a1, b1, acc[1][1], 0, 0, 0);
  }
  #pragma unroll
  for (int mi = 0; mi < 2; mi++)
    #pragma unroll
    for (int ni = 0; ni < 2; ni++)
      #pragma unroll
      for (int j = 0; j < 4; j++){
        int row = m0 + wr + mi * 16 + kb * 4 + j;
        int col = wc + ni * 16 + lr;
        M[(size_t)b * 262144 + (size_t)row * 512 + h * 64 + col] = f2b(acc[mi][ni][j]);
      }
}

extern "C" void kernel_launch(void* const* d_in, const int* in_sizes, int n_in,
                              void* d_out, int out_size, void* d_ws, size_t ws_size,
                              hipStream_t stream)
{
  (void)in_sizes; (void)n_in; (void)out_size; (void)ws_size;
  const float* x    = (const float*)d_in[0];
  const float* g1   = (const float*)d_in[1];
  const float* wqkv = (const float*)d_in[2];
  const float* wout = (const float*)d_in[3];
  const float* bout = (const float*)d_in[4];
  const float* g2   = (const float*)d_in[5];
  float* out = (float*)d_out;
  char* ws = (char*)d_ws;

  u16*   xnT   = (u16*)(ws);                          // S1 (dead after gemm_qkv)
  float* P     = (float*)(ws);                        // S1+0, 8MB (after xnT dead)
  u16*   M     = (u16*)(ws + (size_t)8388608);        // S1+8M, 4MB
  u16*   qT    = (u16*)(ws + (size_t)33554432);       // S2
  u16*   kv    = (u16*)(ws + (size_t)67108864);       // S3
  u16*   wbf   = (u16*)(ws + (size_t)134217728);      // E: wq+wkv bf16 (1.5MB)
  u16*   wkvbf = wbf + (size_t)512 * 512;
  u16*   woutbf= (u16*)(ws + (size_t)135790592);      // 512KB
  float* sden  = (float*)(ws + (size_t)136314880);    // 16KB

  // 1) weights->bf16 (g1 folded) + fused rms1 (vectorized) -> xnT + zero sden
  kprep<<<2048, 256, 0, stream>>>(wqkv, wout, g1, wbf, woutbf, x, xnT, sden);
  // 2) merged: kv_b = Wkv @ xn_b (blocks 0-2047) + qT = softmax_d(xnT@Wq^T)/8
  gemm_qkv<<<3072, 256, 0, stream>>>(wkvbf, wbf, xnT, kv, qT);
  // 3) ctx split-K(8) partials (unnormalized exp(k); sden accumulated inline)
  gemm_ctx<<<dim3(1, 1, 512), 256, 0, stream>>>(kv, P, sden);
  // 4) reduce partials, normalize by sden, fold W_out: M_b = Wout_h @ ctx_bh
  kctxw<<<dim3(1, 8, 64), 256, 0, stream>>>(P, sden, woutbf, M);
  // 5) fused: out2 = qT @ M_b^T + bias, rms2, transposed f32 store -> d_out
  gemm_outrms<<<dim3(32, 8), 512, 0, stream>>>(qT, M, bout, g2, out);
}